// Round 10
// baseline (303.394 us; speedup 1.0000x reference)
//
#include <hip/hip_runtime.h>
#include <hip/hip_bf16.h>

// SchNet forward on MI355X.
// W(d) -> 4096-bin nearest-neighbor bf16 table; ELL (packed col|bin) for
// atomic-free segment sum; telescoped linear residual (composed weights);
// bf16 MFMA; bf16 data plane.
// R10: (a) t1 deleted -- agg1 gathers tv[charges[c]] (25.6KB, L1-hot) and the
//      GEMM adds Cin = tv[charges[row]] in its epilogue; (b) k_agg processes
//      2 nodes/wave with 8B uint2 loads (halves per-edge instr cost);
//      (c) edge scatter kernel standalone (write-amp floor ~55us accepted).

#define NN 50000      // nodes
#define NE 800000     // edges
#define NGR 512       // graphs
#define HD 128        // hidden
#define FD 128        // filters
#define GG 50         // gaussians
#define VOCAB 100
#define NB 4096       // table bins (nearest-neighbor)
#define DMAXT 12.0f   // table covers [0,12]
#define ELLS 80       // ELL stride; deg ~ Poisson(16)
#define SENT 50000u   // sentinel col (t2 row 50000 = 0; agg1 maps to tv row 100 = 0)
#define ASTR 136      // LDS row stride in bf16 elems

#define DELTA (10.0f/49.0f)
#define COEFF (-0.5f/(DELTA*DELTA))

// k_prep grid segments
#define TB_B 4096
#define WF_B 128
#define WH_B 64
#define TV_B 100
#define HG_B 100
#define BV_B 2
#define C4_B 391
#define Z_B  396      // ceil((NN+NGR+64+64)/128)
// edge kernel
#define EDGB 3125     // NE/256

typedef __attribute__((ext_vector_type(8))) short bf16x8;
typedef __attribute__((ext_vector_type(4))) float f32x4;

static __device__ __forceinline__ float sspf(float x) {
    return fmaxf(x, 0.0f) + log1pf(expf(-fabsf(x))) - 0.69314718055994531f;
}
static __device__ __forceinline__ float asf(unsigned int u) {
    union { unsigned int u; float f; } v; v.u = u; return v.f;
}
static __device__ __forceinline__ float bf2f(unsigned short b) {
    union { unsigned int u; float f; } v; v.u = ((unsigned int)b) << 16; return v.f;
}
static __device__ __forceinline__ unsigned short f2bf(float f) {
    union { float f; unsigned int u; } v; v.f = f;
    unsigned int r = v.u + 0x7FFF + ((v.u >> 16) & 1);   // round-nearest-even
    return (unsigned short)(r >> 16);
}

// Fused prep (segments by blockIdx.x): Tb table; wfT=(w_nm@w_el)^T;
// whT=(w_nm@w_g1)^T; tv=emb@w_el; hg=emb@w_g1; bv=b_nm@w_el,
// gvec=b_g1+2*b_nm@w_g1; coords->float4; zero deg/out/t2-sentinel/tv-row100.
__global__ __launch_bounds__(128) void k_prep(const float* __restrict__ w_e1,
                                              const float* __restrict__ b_e1,
                                              const float* __restrict__ w_e2,
                                              const float* __restrict__ b_e2,
                                              const float* __restrict__ w_el,
                                              const float* __restrict__ w_nm,
                                              const float* __restrict__ b_nm,
                                              const float* __restrict__ w_g1,
                                              const float* __restrict__ b_g1,
                                              const float* __restrict__ emb,
                                              const float* __restrict__ coords,
                                              unsigned int* __restrict__ Tb,
                                              unsigned short* __restrict__ wfT,
                                              unsigned short* __restrict__ whT,
                                              unsigned short* __restrict__ tv,
                                              unsigned short* __restrict__ hg,
                                              float* __restrict__ bv,
                                              float* __restrict__ gvec,
                                              float4* __restrict__ c4,
                                              int* __restrict__ deg,
                                              float* __restrict__ out,
                                              unsigned int* __restrict__ t2s,
                                              unsigned int* __restrict__ tvz) {
    __shared__ float sbuf[320];
    int bid = blockIdx.x, tx = threadIdx.x;
    if (bid < TB_B) {
        float* a = sbuf;            // 50
        float* y = sbuf + 64;       // 128
        float* z = sbuf + 192;      // 128
        float d = (float)bid * (DMAXT / (float)(NB - 1));
        if (tx < GG) {
            float o = (float)tx * DELTA;
            float tt = d - o;
            a[tx] = expf(COEFF * tt * tt);
        }
        __syncthreads();
        float acc = b_e1[tx];
        #pragma unroll 10
        for (int g = 0; g < GG; ++g) acc = fmaf(a[g], w_e1[g * FD + tx], acc);
        y[tx] = sspf(acc);
        __syncthreads();
        float acc2 = b_e2[tx];
        #pragma unroll 8
        for (int k = 0; k < FD; ++k) acc2 = fmaf(y[k], w_e2[k * FD + tx], acc2);
        z[tx] = acc2;
        __syncthreads();
        if (tx < 64)
            Tb[bid * 64 + tx] = (unsigned int)f2bf(z[2 * tx])
                              | ((unsigned int)f2bf(z[2 * tx + 1]) << 16);
    } else if (bid < TB_B + WF_B) {
        int n = bid - TB_B;
        sbuf[tx] = w_el[tx * 128 + n];
        __syncthreads();
        float acc = 0.f;
        #pragma unroll 8
        for (int j = 0; j < 128; ++j) acc = fmaf(w_nm[tx * 128 + j], sbuf[j], acc);
        wfT[n * 128 + tx] = f2bf(acc);
    } else if (bid < TB_B + WF_B + WH_B) {
        int n = bid - TB_B - WF_B;
        sbuf[tx] = w_g1[tx * 64 + n];
        __syncthreads();
        float acc = 0.f;
        #pragma unroll 8
        for (int j = 0; j < 128; ++j) acc = fmaf(w_nm[tx * 128 + j], sbuf[j], acc);
        whT[n * 128 + tx] = f2bf(acc);
    } else if (bid < TB_B + WF_B + WH_B + TV_B) {
        int r = bid - TB_B - WF_B - WH_B;
        sbuf[tx] = emb[r * HD + tx];
        __syncthreads();
        float acc = 0.f;
        #pragma unroll 8
        for (int k = 0; k < HD; ++k) acc = fmaf(sbuf[k], w_el[k * FD + tx], acc);
        tv[r * FD + tx] = f2bf(acc);
    } else if (bid < TB_B + WF_B + WH_B + TV_B + HG_B) {
        int c = bid - TB_B - WF_B - WH_B - TV_B;
        sbuf[tx] = emb[c * HD + tx];
        __syncthreads();
        if (tx < 64) {
            float acc = 0.f;
            #pragma unroll 8
            for (int k = 0; k < HD; ++k) acc = fmaf(sbuf[k], w_g1[k * 64 + tx], acc);
            hg[c * 64 + tx] = f2bf(acc);
        }
    } else if (bid < TB_B + WF_B + WH_B + TV_B + HG_B + BV_B) {
        int which = bid - (TB_B + WF_B + WH_B + TV_B + HG_B);
        if (which == 0) {
            float acc = 0.f;
            for (int k = 0; k < HD; ++k) acc = fmaf(b_nm[k], w_el[k * FD + tx], acc);
            bv[tx] = acc;
        } else if (tx < 64) {
            float acc = 0.f;
            for (int k = 0; k < HD; ++k) acc = fmaf(b_nm[k], w_g1[k * 64 + tx], acc);
            gvec[tx] = b_g1[tx] + 2.0f * acc;
        }
    } else if (bid < TB_B + WF_B + WH_B + TV_B + HG_B + BV_B + C4_B) {
        int i = (bid - (TB_B + WF_B + WH_B + TV_B + HG_B + BV_B)) * 128 + tx;
        if (i < NN)
            c4[i] = make_float4(coords[3 * i], coords[3 * i + 1],
                                coords[3 * i + 2], 0.f);
    } else {
        int j = (bid - (TB_B + WF_B + WH_B + TV_B + HG_B + BV_B + C4_B)) * 128 + tx;
        if (j < NN) deg[j] = 0;
        else if (j < NN + NGR) out[j - NN] = 0.f;
        else if (j < NN + NGR + 64) t2s[j - NN - NGR] = 0u;
        else if (j < NN + NGR + 128) tvz[j - NN - NGR - 64] = 0u;
    }
}

// Edge bucketing: pack (col 16b | bin 12b) into ELL slot of row.
__global__ __launch_bounds__(256) void k_edge(const int* __restrict__ eidx,
                                              const float4* __restrict__ c4,
                                              int* __restrict__ deg,
                                              unsigned int* __restrict__ emll) {
    int e = blockIdx.x * 256 + threadIdx.x;    // exactly NE
    int r = eidx[e];
    int c = eidx[NE + e];
    float4 pr = c4[r], pc = c4[c];
    float dx = pr.x - pc.x, dy = pr.y - pc.y, dz = pr.z - pc.z;
    float d = sqrtf(dx * dx + dy * dy + dz * dz);
    float u = d * ((float)(NB - 1) / DMAXT);
    int b = (int)(u + 0.5f);
    if (b > NB - 1) b = NB - 1;
    unsigned int em = (unsigned int)c | ((unsigned int)b << 16);
    int pos = atomicAdd(&deg[r], 1);
    if (pos < ELLS) emll[r * ELLS + pos] = em;
}

// LDS-staged MFMA GEMM: Out[M,128](bf16) = A(bf16) @ BT^T + bias
//                       + tvrows[chmap[row]] (vocab-gathered Cin).
__global__ __launch_bounds__(256) void k_gemm(const unsigned short* __restrict__ A,
                                              const unsigned short* __restrict__ BT,
                                              const int* __restrict__ chmap,
                                              const unsigned short* __restrict__ Crows,
                                              const float* __restrict__ bias,
                                              unsigned short* __restrict__ Out,
                                              int M) {
    __shared__ unsigned short Als[64 * ASTR];    // 17.4 KB
    __shared__ unsigned short Bls[128 * ASTR];   // 34.8 KB
    int tx = threadIdx.x;
    int row0 = blockIdx.x * 64;
    #pragma unroll
    for (int q = 0; q < 4; ++q) {
        int l = tx + q * 256;
        int r = l >> 4, c = l & 15;
        int grow = row0 + r;
        uint4 v = make_uint4(0u, 0u, 0u, 0u);
        if (grow < M) v = *(const uint4*)(A + (size_t)grow * 128 + c * 8);
        *(uint4*)(&Als[r * ASTR + c * 8]) = v;
    }
    #pragma unroll
    for (int q = 0; q < 8; ++q) {
        int l = tx + q * 256;
        int r = l >> 4, c = l & 15;
        *(uint4*)(&Bls[r * ASTR + c * 8]) = *(const uint4*)(BT + (size_t)r * 128 + c * 8);
    }
    __syncthreads();

    int w = tx >> 6, lane = tx & 63, m = lane & 15, quad = lane >> 4;
    f32x4 acc[8];
    #pragma unroll
    for (int ct = 0; ct < 8; ++ct) acc[ct] = (f32x4){0.f, 0.f, 0.f, 0.f};
    #pragma unroll
    for (int s = 0; s < 4; ++s) {
        bf16x8 a = *(const bf16x8*)(&Als[(w * 16 + m) * ASTR + s * 32 + quad * 8]);
        #pragma unroll
        for (int ct = 0; ct < 8; ++ct) {
            bf16x8 b = *(const bf16x8*)(&Bls[(ct * 16 + m) * ASTR + s * 32 + quad * 8]);
            acc[ct] = __builtin_amdgcn_mfma_f32_16x16x32_bf16(a, b, acc[ct], 0, 0, 0);
        }
    }
    #pragma unroll
    for (int r = 0; r < 4; ++r) {
        int grow = row0 + w * 16 + quad * 4 + r;
        if (grow >= M) continue;
        int ch = chmap ? chmap[grow] : 0;
        #pragma unroll
        for (int ct = 0; ct < 8; ++ct) {
            int col = ct * 16 + m;
            float v = acc[ct][r];
            if (bias)  v += bias[col];
            if (chmap) v += bf2f(Crows[(size_t)ch * 128 + col]);
            Out[(size_t)grow * 128 + col] = f2bf(v);
        }
    }
}

// Aggregation: 2 nodes per wave (32 lanes x 4 elems, 8B loads).
// out[i,:] = sum_j rows(col_j) * Tb[bin_j,:] (+ addin[i,:])
// chmap!=null: row source = tsrc[chmap[c]] (vocab gather, SENT->VOCAB row 0).
__global__ __launch_bounds__(256) void k_agg(const unsigned short* __restrict__ tsrc,
                                             const int* __restrict__ chmap,
                                             const unsigned int* __restrict__ Tb,
                                             const int* __restrict__ deg,
                                             const unsigned int* __restrict__ emll,
                                             const unsigned short* __restrict__ addin,
                                             unsigned short* __restrict__ outb) {
    int wave = (blockIdx.x * blockDim.x + threadIdx.x) >> 6;
    int lane = threadIdx.x & 63;
    int node = wave * 2 + (lane >> 5);          // grid covers exactly NN/2 waves
    int sub = lane & 31;
    int dg = min(deg[node], ELLS);
    int dgo = __shfl_xor(dg, 32, 64);
    int dgup = (max(dg, dgo) + 7) & ~7;
    const int base = node * ELLS;
    float a0 = 0.f, a1 = 0.f, a2 = 0.f, a3 = 0.f;
    for (int j0 = 0; j0 < dgup; j0 += 32) {
        unsigned int myem = SENT;               // c=SENT, bin=0
        if (sub < dg - j0) myem = emll[base + j0 + sub];
        int chunk = min(32, dgup - j0);
        for (int j = 0; j < chunk; j += 8) {
            #pragma unroll
            for (int u = 0; u < 8; ++u) {
                unsigned int em = (unsigned int)__shfl((int)myem, (lane & 32) + j + u, 64);
                int c = (int)(em & 0xFFFFu);
                int b = (int)(em >> 16);
                const unsigned short* rp;
                if (chmap) {
                    int ch = (c == (int)SENT) ? VOCAB : chmap[c];
                    rp = tsrc + (size_t)ch * HD;
                } else {
                    rp = tsrc + (size_t)c * HD;
                }
                uint2 tvv = *(const uint2*)(rp + sub * 4);
                uint2 q   = *(const uint2*)(Tb + (size_t)b * 64 + sub * 2);
                a0 = fmaf(asf(tvv.x << 16),          asf(q.x << 16),          a0);
                a1 = fmaf(asf(tvv.x & 0xFFFF0000u),  asf(q.x & 0xFFFF0000u),  a1);
                a2 = fmaf(asf(tvv.y << 16),          asf(q.y << 16),          a2);
                a3 = fmaf(asf(tvv.y & 0xFFFF0000u),  asf(q.y & 0xFFFF0000u),  a3);
            }
        }
    }
    if (addin) {
        uint2 av = *(const uint2*)(addin + (size_t)node * FD + sub * 4);
        a0 += asf(av.x << 16);
        a1 += asf(av.x & 0xFFFF0000u);
        a2 += asf(av.y << 16);
        a3 += asf(av.y & 0xFFFF0000u);
    }
    uint2 o;
    o.x = (unsigned int)f2bf(a0) | ((unsigned int)f2bf(a1) << 16);
    o.y = (unsigned int)f2bf(a2) | ((unsigned int)f2bf(a3) << 16);
    *(uint2*)(outb + (size_t)node * FD + sub * 4) = o;
}

// Readout: G1 = asum@w_h + hg[charge[row]] + gvec; p = ssp(G1)@w_g2 + b_g2;
// atomicAdd(out[batch[row]], p).
__global__ __launch_bounds__(256) void k_readout(const unsigned short* __restrict__ asum,
                                                 const int* __restrict__ charges,
                                                 const int* __restrict__ batch,
                                                 const unsigned short* __restrict__ whT,
                                                 const unsigned short* __restrict__ hg,
                                                 const float* __restrict__ gvec,
                                                 const float* __restrict__ w_g2,
                                                 const float* __restrict__ b_g2,
                                                 float* __restrict__ out) {
    __shared__ unsigned short Als[64 * ASTR];
    __shared__ unsigned short Bls[64 * ASTR];
    int tx = threadIdx.x;
    int row0 = blockIdx.x * 64;
    #pragma unroll
    for (int q = 0; q < 4; ++q) {
        int l = tx + q * 256;
        int r = l >> 4, c = l & 15;
        int grow = row0 + r;
        uint4 v = make_uint4(0u, 0u, 0u, 0u);
        if (grow < NN) v = *(const uint4*)(asum + (size_t)grow * 128 + c * 8);
        *(uint4*)(&Als[r * ASTR + c * 8]) = v;
    }
    #pragma unroll
    for (int q = 0; q < 4; ++q) {
        int l = tx + q * 256;
        int r = l >> 4, c = l & 15;
        *(uint4*)(&Bls[r * ASTR + c * 8]) = *(const uint4*)(whT + (size_t)r * 128 + c * 8);
    }
    __syncthreads();

    int w = tx >> 6, lane = tx & 63, m = lane & 15, quad = lane >> 4;
    f32x4 acc[4];
    #pragma unroll
    for (int ct = 0; ct < 4; ++ct) acc[ct] = (f32x4){0.f, 0.f, 0.f, 0.f};
    #pragma unroll
    for (int s = 0; s < 4; ++s) {
        bf16x8 a = *(const bf16x8*)(&Als[(w * 16 + m) * ASTR + s * 32 + quad * 8]);
        #pragma unroll
        for (int ct = 0; ct < 4; ++ct) {
            bf16x8 b = *(const bf16x8*)(&Bls[(ct * 16 + m) * ASTR + s * 32 + quad * 8]);
            acc[ct] = __builtin_amdgcn_mfma_f32_16x16x32_bf16(a, b, acc[ct], 0, 0, 0);
        }
    }
    float gv[4], w2[4];
    #pragma unroll
    for (int ct = 0; ct < 4; ++ct) {
        int col = ct * 16 + m;
        gv[ct] = gvec[col];
        w2[ct] = w_g2[col];
    }
    float bg2 = b_g2[0];
    #pragma unroll
    for (int r = 0; r < 4; ++r) {
        int row = row0 + w * 16 + quad * 4 + r;
        int rowc = row < NN ? row : NN - 1;
        int ch = charges[rowc];
        float p = 0.f;
        #pragma unroll
        for (int ct = 0; ct < 4; ++ct) {
            int col = ct * 16 + m;
            float g1 = acc[ct][r] + bf2f(hg[ch * 64 + col]) + gv[ct];
            p += sspf(g1) * w2[ct];
        }
        p += __shfl_down(p, 8, 16);
        p += __shfl_down(p, 4, 16);
        p += __shfl_down(p, 2, 16);
        p += __shfl_down(p, 1, 16);
        if (m == 0 && row < NN) atomicAdd(&out[batch[row]], p + bg2);
    }
}

extern "C" void kernel_launch(void* const* d_in, const int* in_sizes, int n_in,
                              void* d_out, int out_size, void* d_ws, size_t ws_size,
                              hipStream_t stream) {
    const int*   charges = (const int*)d_in[0];
    const float* coords  = (const float*)d_in[1];
    const int*   eidx    = (const int*)d_in[2];
    const int*   batch   = (const int*)d_in[3];
    const float* emb     = (const float*)d_in[4];
    const float* w_e1    = (const float*)d_in[5];
    const float* b_e1    = (const float*)d_in[6];
    const float* w_e2    = (const float*)d_in[7];
    const float* b_e2    = (const float*)d_in[8];
    const float* w_el    = (const float*)d_in[9];
    const float* w_nm    = (const float*)d_in[10];
    const float* b_nm    = (const float*)d_in[11];
    const float* w_g1    = (const float*)d_in[12];
    const float* b_g1    = (const float*)d_in[13];
    const float* w_g2    = (const float*)d_in[14];
    const float* b_g2    = (const float*)d_in[15];
    float* out = (float*)d_out;

    char* ws = (char*)d_ws;
    size_t off = 0;
    auto alloc = [&](size_t bytes) -> char* {
        char* p = ws + off;
        off += (bytes + 255) & ~(size_t)255;
        return p;
    };
    unsigned short* t2   = (unsigned short*)alloc((size_t)(NN + 1) * HD * 2); // +sentinel
    unsigned short* agg1 = (unsigned short*)alloc((size_t)NN * FD * 2);
    unsigned short* asum = (unsigned short*)alloc((size_t)NN * FD * 2);
    unsigned int*   Tb   = (unsigned int*)alloc((size_t)NB * 64 * 4);         // 1 MB
    int*            deg  = (int*)alloc((size_t)NN * 4);
    unsigned int*   emll = (unsigned int*)alloc((size_t)NN * ELLS * 4);       // 16 MB
    unsigned short* wfT  = (unsigned short*)alloc((size_t)128 * 128 * 2);
    unsigned short* whT  = (unsigned short*)alloc((size_t)64 * 128 * 2);
    unsigned short* tv   = (unsigned short*)alloc((size_t)(VOCAB + 1) * 128 * 2); // +zero row
    unsigned short* hg   = (unsigned short*)alloc((size_t)VOCAB * 64 * 2);
    float*          bv   = (float*)alloc(128 * 4);
    float*          gvec = (float*)alloc(64 * 4);
    float4*         c4   = (float4*)alloc((size_t)NN * 16);
    if (off > ws_size) return;  // workspace too small -> fail visibly, no OOB

    k_prep<<<TB_B + WF_B + WH_B + TV_B + HG_B + BV_B + C4_B + Z_B, 128, 0, stream>>>(
        w_e1, b_e1, w_e2, b_e2, w_el, w_nm, b_nm, w_g1, b_g1, emb, coords,
        Tb, wfT, whT, tv, hg, bv, gvec, c4, deg, out,
        (unsigned int*)(t2 + (size_t)NN * HD),
        (unsigned int*)(tv + (size_t)VOCAB * 128));
    k_edge<<<EDGB, 256, 0, stream>>>(eidx, c4, deg, emll);

    // agg1[i] = sum_j tv[charges[col_j]] * Tb[bin_j]
    k_agg<<<NN / 8, 256, 0, stream>>>(tv, charges, Tb, deg, emll, nullptr, agg1);
    // t2 = tv[charges[row]] + agg1 @ w_f + b_nm@w_el
    k_gemm<<<(NN + 63) / 64, 256, 0, stream>>>(agg1, wfT, charges, tv, bv, t2, NN);
    // asum = agg1 + AGG(t2)
    k_agg<<<NN / 8, 256, 0, stream>>>(t2, nullptr, Tb, deg, emll, agg1, asum);

    k_readout<<<(NN + 63) / 64, 256, 0, stream>>>(asum, charges, batch, whT, hg,
                                                  gvec, w_g2, b_g2, out);
}